// Round 1
// baseline (11529.315 us; speedup 1.0000x reference)
//
#include <hip/hip_runtime.h>
#include <hip/hip_bf16.h>

typedef __attribute__((ext_vector_type(8))) short short8;
typedef __attribute__((ext_vector_type(4))) float f32x4;

#define T_STEPS 512
#define BATCH   256
#define HDIM    1024
#define IDIM    1024
#define KDIM    2048   // I + H
#define GDIM    4096   // 4*H

__device__ __forceinline__ float sigmoidf_(float x) {
  return 1.0f / (1.0f + __expf(-x));
}
__device__ __forceinline__ float tanh_(float x) {
  return 2.0f / (1.0f + __expf(-2.0f * x)) - 1.0f;
}
__device__ __forceinline__ short f2bf(float f) {
  __hip_bfloat16 h = __float2bfloat16(f);
  short s;
  __builtin_memcpy(&s, &h, sizeof(short));
  return s;
}

// ---------------------------------------------------------------------------
// Pack weights: W_comb[g][k] bf16 (k<1024 -> Wx, else Wh), Wfc bf16, bias=bx+bh
// ---------------------------------------------------------------------------
__global__ void pack_kernel(const float* __restrict__ Wx, const float* __restrict__ Wh,
                            const float* __restrict__ bx, const float* __restrict__ bh,
                            const float* __restrict__ Wfc,
                            __hip_bfloat16* __restrict__ Wc,
                            __hip_bfloat16* __restrict__ Wfcb,
                            float* __restrict__ biasc)
{
  const int stride = gridDim.x * blockDim.x;
  const int tid0 = blockIdx.x * blockDim.x + threadIdx.x;
  for (int i = tid0; i < GDIM * KDIM; i += stride) {
    int g = i >> 11, k = i & (KDIM - 1);
    float v = (k < IDIM) ? Wx[g * IDIM + k] : Wh[g * HDIM + (k - IDIM)];
    Wc[i] = __float2bfloat16(v);
  }
  for (int i = tid0; i < 1024 * 1024; i += stride)
    Wfcb[i] = __float2bfloat16(Wfc[i]);
  for (int i = tid0; i < GDIM; i += stride)
    biasc[i] = bx[i] + bh[i];
}

// ---------------------------------------------------------------------------
// One LSTM timestep: gates = [x_t | h] @ Wc^T (+bias), then fused peephole cell.
// Grid: 256 blocks x 512 threads. Block tile: 64 rows (batch) x 64 cols
// (16 cols per gate x 4 gates). K=2048 split across wave halves (kh).
// ---------------------------------------------------------------------------
__global__ __launch_bounds__(512, 1)
void lstm_step(const float* __restrict__ x,
               const __hip_bfloat16* __restrict__ Wc,
               const float* __restrict__ biasc,
               const float* __restrict__ c2c,
               const __hip_bfloat16* __restrict__ h_in,
               __hip_bfloat16* __restrict__ h_out,
               float* __restrict__ c_st,
               int t)
{
  // A tile: 64 rows x 128 k (bf16) = 1024 16B-granules (16KB). B tile same.
  __shared__ short8 As8[1024];
  __shared__ short8 Bs8[1024];

  const int tid  = threadIdx.x;
  const int wave = tid >> 6;
  const int lane = tid & 63;

  // XCD-aware tile mapping: each XCD gets a contiguous set of ntiles so its
  // W rows stay L2-resident across all 512 steps.
  const int bid   = blockIdx.x;
  const int xcd   = bid & 7;
  const int idx   = bid >> 3;
  const int ntile = xcd * 8 + (idx & 7);   // 0..63
  const int mtile = idx >> 3;              // 0..3
  const int b0 = mtile * 64;
  const int j0 = ntile * 16;

  // ---- staging: thread owns granules g0=tid and g1=tid+512 of A and B ----
  const int r0  = tid >> 4;        // rows r0 and r0+32
  const int cg0 = tid & 15;        // granule-col (8 bf16 each)

  // LDS write slots (XOR swizzle on granule-col within each row; (r+32)&7==r&7)
  short8* aw0 = &As8[r0 * 16 + (cg0 ^ (r0 & 7))];
  short8* aw1 = &As8[(r0 + 32) * 16 + (cg0 ^ (r0 & 7))];
  short8* bw0 = &Bs8[r0 * 16 + (cg0 ^ (r0 & 7))];
  short8* bw1 = &Bs8[(r0 + 32) * 16 + (cg0 ^ (r0 & 7))];

  // global sources
  const int Arow0 = b0 + r0, Arow1 = b0 + r0 + 32;
  const int Brow0 = ((r0 >> 4) * HDIM) + j0 + (r0 & 15);         // gates 0,1
  const int Brow1 = (((r0 + 32) >> 4) * HDIM) + j0 + (r0 & 15);  // gates 2,3
  const __hip_bfloat16* Wp0 = Wc + (size_t)Brow0 * KDIM + cg0 * 8;
  const __hip_bfloat16* Wp1 = Wc + (size_t)Brow1 * KDIM + cg0 * 8;
  const float* xp0 = x + ((size_t)Arow0 * T_STEPS + t) * IDIM + cg0 * 8;
  const float* xp1 = x + ((size_t)Arow1 * T_STEPS + t) * IDIM + cg0 * 8;
  const __hip_bfloat16* hp0 = h_in + (size_t)Arow0 * HDIM + cg0 * 8;
  const __hip_bfloat16* hp1 = h_in + (size_t)Arow1 * HDIM + cg0 * 8;

  // prefetch registers
  f32x4 xv0, xv1, xv2, xv3;
  short8 hv0, hv1, bv0, bv1;

#define LOADS(KC)                                                          \
  do {                                                                     \
    bv0 = *(const short8*)(const void*)(Wp0 + (size_t)(KC) * 128);         \
    bv1 = *(const short8*)(const void*)(Wp1 + (size_t)(KC) * 128);         \
    if ((KC) < 8) {                                                        \
      const float* p0_ = xp0 + (size_t)(KC) * 128;                         \
      const float* p1_ = xp1 + (size_t)(KC) * 128;                         \
      xv0 = *(const f32x4*)(const void*)(p0_);                             \
      xv1 = *(const f32x4*)(const void*)(p0_ + 4);                         \
      xv2 = *(const f32x4*)(const void*)(p1_);                             \
      xv3 = *(const f32x4*)(const void*)(p1_ + 4);                         \
    } else {                                                               \
      hv0 = *(const short8*)(const void*)(hp0 + (size_t)((KC) - 8) * 128); \
      hv1 = *(const short8*)(const void*)(hp1 + (size_t)((KC) - 8) * 128); \
    }                                                                      \
  } while (0)

#define WRITE_LDS(KC)                                                      \
  do {                                                                     \
    *bw0 = bv0; *bw1 = bv1;                                                \
    if ((KC) < 8) {                                                        \
      short8 a0_, a1_;                                                     \
      _Pragma("unroll")                                                    \
      for (int e = 0; e < 4; ++e) {                                        \
        a0_[e]     = f2bf(xv0[e]);                                         \
        a0_[e + 4] = f2bf(xv1[e]);                                         \
        a1_[e]     = f2bf(xv2[e]);                                         \
        a1_[e + 4] = f2bf(xv3[e]);                                         \
      }                                                                    \
      *aw0 = a0_; *aw1 = a1_;                                              \
    } else {                                                               \
      *aw0 = hv0; *aw1 = hv1;                                              \
    }                                                                      \
  } while (0)

  // ---- compute assignment ----
  const int rf = wave & 3;   // row-fragment (16 rows)
  const int kh = wave >> 2;  // k-half of each 128-k chunk
  const int arow = rf * 16 + (lane & 15);

  f32x4 acc[4];
#pragma unroll
  for (int f = 0; f < 4; ++f) acc[f] = (f32x4){0.f, 0.f, 0.f, 0.f};

  LOADS(0);
#pragma unroll 1
  for (int kc = 0; kc < 16; ++kc) {
    __syncthreads();
    WRITE_LDS(kc);
    if (kc < 15) LOADS(kc + 1);
    __syncthreads();
#pragma unroll
    for (int ss = 0; ss < 2; ++ss) {
      const int colg = kh * 8 + ss * 4 + (lane >> 4);
      short8 af = As8[arow * 16 + (colg ^ (arow & 7))];
#pragma unroll
      for (int f = 0; f < 4; ++f) {
        const int br = f * 16 + (lane & 15);
        short8 bfq = Bs8[br * 16 + (colg ^ (br & 7))];
        acc[f] = __builtin_amdgcn_mfma_f32_16x16x32_bf16(af, bfq, acc[f], 0, 0, 0);
      }
    }
  }

  // ---- reduce k-halves, then fused LSTM cell ----
  __syncthreads();
  float* red = (float*)&As8[0];  // 64x64 f32 = 16KB
  const int drow = (lane >> 4) * 4;
  const int dcol = lane & 15;
  if (kh == 1) {
#pragma unroll
    for (int f = 0; f < 4; ++f)
#pragma unroll
      for (int r = 0; r < 4; ++r)
        red[(rf * 16 + drow + r) * 64 + f * 16 + dcol] = acc[f][r];
  }
  __syncthreads();
  if (kh == 0) {
#pragma unroll
    for (int f = 0; f < 4; ++f)
#pragma unroll
      for (int r = 0; r < 4; ++r)
        acc[f][r] += red[(rf * 16 + drow + r) * 64 + f * 16 + dcol];

    const int j = j0 + dcol;
    const float bi = biasc[j];
    const float bf = biasc[HDIM + j];
    const float bg = biasc[2 * HDIM + j];
    const float bo = biasc[3 * HDIM + j];
    const float ci = c2c[j];
    const float cf = c2c[HDIM + j];
    const float co = c2c[2 * HDIM + j];
#pragma unroll
    for (int r = 0; r < 4; ++r) {
      const int b = b0 + rf * 16 + drow + r;
      float cp = c_st[(size_t)b * HDIM + j];
      float ig = sigmoidf_(acc[0][r] + bi + ci * cp);
      float fg = sigmoidf_(acc[1][r] + bf + cf * cp);
      float gg = tanh_(acc[2][r] + bg);
      float cn = fg * cp + ig * gg;
      float og = sigmoidf_(acc[3][r] + bo + co * cn);
      float hn = og * tanh_(cn);
      c_st[(size_t)b * HDIM + j] = cn;
      h_out[(size_t)b * HDIM + j] = __float2bfloat16(hn);
    }
  }
#undef LOADS
#undef WRITE_LDS
}

// ---------------------------------------------------------------------------
// Final FC: out[b][o] = h[b][:] . Wfc[o][:] + bfc[o]   (M=256,N=1024,K=1024)
// Grid: 64 blocks x 256 threads, 64x64 tiles.
// ---------------------------------------------------------------------------
__global__ __launch_bounds__(256, 1)
void fc_kernel(const __hip_bfloat16* __restrict__ h,
               const __hip_bfloat16* __restrict__ Wfc,
               const float* __restrict__ bfc,
               float* __restrict__ out)
{
  __shared__ short8 As8[512];  // 64 rows x 8 granules (64 k)
  __shared__ short8 Bs8[512];

  const int tid = threadIdx.x;
  const int wave = tid >> 6;
  const int lane = tid & 63;
  const int mtile = blockIdx.x >> 4;
  const int otile = blockIdx.x & 15;
  const int b0 = mtile * 64, o0 = otile * 64;

  const int r0 = tid >> 3;   // rows r0, r0+32
  const int cg0 = tid & 7;

  f32x4 acc[4];
#pragma unroll
  for (int f = 0; f < 4; ++f) acc[f] = (f32x4){0.f, 0.f, 0.f, 0.f};

#pragma unroll 1
  for (int kc = 0; kc < 16; ++kc) {
    __syncthreads();
    As8[r0 * 8 + (cg0 ^ (r0 & 7))] =
        *(const short8*)(const void*)(h + (size_t)(b0 + r0) * HDIM + kc * 64 + cg0 * 8);
    As8[(r0 + 32) * 8 + (cg0 ^ (r0 & 7))] =
        *(const short8*)(const void*)(h + (size_t)(b0 + r0 + 32) * HDIM + kc * 64 + cg0 * 8);
    Bs8[r0 * 8 + (cg0 ^ (r0 & 7))] =
        *(const short8*)(const void*)(Wfc + (size_t)(o0 + r0) * HDIM + kc * 64 + cg0 * 8);
    Bs8[(r0 + 32) * 8 + (cg0 ^ (r0 & 7))] =
        *(const short8*)(const void*)(Wfc + (size_t)(o0 + r0 + 32) * HDIM + kc * 64 + cg0 * 8);
    __syncthreads();
#pragma unroll
    for (int s = 0; s < 2; ++s) {
      const int colg = s * 4 + (lane >> 4);
      const int ar = wave * 16 + (lane & 15);
      short8 af = As8[ar * 8 + (colg ^ (ar & 7))];
#pragma unroll
      for (int f = 0; f < 4; ++f) {
        const int br = f * 16 + (lane & 15);
        short8 bfq = Bs8[br * 8 + (colg ^ (br & 7))];
        acc[f] = __builtin_amdgcn_mfma_f32_16x16x32_bf16(af, bfq, acc[f], 0, 0, 0);
      }
    }
  }

  const int dcol = lane & 15;
  const int drow = (lane >> 4) * 4;
#pragma unroll
  for (int f = 0; f < 4; ++f) {
    const int o = o0 + f * 16 + dcol;
    const float bias = bfc[o];
#pragma unroll
    for (int r = 0; r < 4; ++r) {
      const int b = b0 + wave * 16 + drow + r;
      out[(size_t)b * 1024 + o] = acc[f][r] + bias;
    }
  }
}

// ---------------------------------------------------------------------------
extern "C" void kernel_launch(void* const* d_in, const int* in_sizes, int n_in,
                              void* d_out, int out_size, void* d_ws, size_t ws_size,
                              hipStream_t stream)
{
  const float* x   = (const float*)d_in[0];
  const float* Wx  = (const float*)d_in[1];
  const float* bx  = (const float*)d_in[2];
  const float* Wh  = (const float*)d_in[3];
  const float* bh  = (const float*)d_in[4];
  const float* c2c = (const float*)d_in[5];
  const float* Wfc = (const float*)d_in[6];
  const float* bfc = (const float*)d_in[7];
  float* out = (float*)d_out;

  char* ws = (char*)d_ws;
  __hip_bfloat16* Wc    = (__hip_bfloat16*)(ws);                         // 16 MB
  __hip_bfloat16* Wfcb  = (__hip_bfloat16*)(ws + (16u << 20));           // 2 MB
  float*          biasc = (float*)(ws + (18u << 20));                    // 16 KB
  __hip_bfloat16* hb0   = (__hip_bfloat16*)(ws + (19u << 20));           // 512 KB
  __hip_bfloat16* hb1   = (__hip_bfloat16*)(ws + (19u << 20) + (1u << 19)); // 512 KB
  float*          c_st  = (float*)(ws + (20u << 20));                    // 1 MB

  hipMemsetAsync(hb0, 0, (size_t)BATCH * HDIM * sizeof(__hip_bfloat16), stream);
  hipMemsetAsync(c_st, 0, (size_t)BATCH * HDIM * sizeof(float), stream);

  pack_kernel<<<2048, 256, 0, stream>>>(Wx, Wh, bx, bh, Wfc, Wc, Wfcb, biasc);

  for (int t = 0; t < T_STEPS; ++t) {
    const __hip_bfloat16* hin = (t & 1) ? hb1 : hb0;
    __hip_bfloat16* hout      = (t & 1) ? hb0 : hb1;
    lstm_step<<<256, 512, 0, stream>>>(x, Wc, biasc, c2c, hin, hout, c_st, t);
  }

  fc_kernel<<<64, 256, 0, stream>>>(hb0, Wfcb, bfc, out);
}

// Round 2
// 8062.523 us; speedup vs baseline: 1.4300x; 1.4300x over previous
//
#include <hip/hip_runtime.h>
#include <hip/hip_bf16.h>

typedef __attribute__((ext_vector_type(8))) short short8;
typedef __attribute__((ext_vector_type(4))) float f32x4;

#define T_STEPS 512
#define BATCH   256
#define HDIM    1024
#define GDIM    4096   // 4*H

__device__ __forceinline__ float sigmoidf_(float x) {
  return 1.0f / (1.0f + __expf(-x));
}
__device__ __forceinline__ float tanh_(float x) {
  return 2.0f / (1.0f + __expf(-2.0f * x)) - 1.0f;
}
__device__ __forceinline__ short f2bf(float f) {
  __hip_bfloat16 h = __float2bfloat16(f);
  short s;
  __builtin_memcpy(&s, &h, sizeof(short));
  return s;
}

// ---------------------------------------------------------------------------
// Pack: Whb = bf16(Wh) [4096][1024]; biasc = bx + bh
// ---------------------------------------------------------------------------
__global__ void pack_kernel(const float* __restrict__ Wh,
                            const float* __restrict__ bx, const float* __restrict__ bh,
                            __hip_bfloat16* __restrict__ Whb,
                            float* __restrict__ biasc)
{
  const int stride = gridDim.x * blockDim.x;
  const int tid0 = blockIdx.x * blockDim.x + threadIdx.x;
  for (int i = tid0; i < GDIM * HDIM; i += stride)
    Whb[i] = __float2bfloat16(Wh[i]);
  for (int i = tid0; i < GDIM; i += stride)
    biasc[i] = bx[i] + bh[i];
}

// ---------------------------------------------------------------------------
// xg GEMM: xg[(t-t0)*256 + b][g] = bf16( x[b][t][:] . Wx[g][:] )
// M = W*256, N = 4096, K = 1024. 128x128 tile, 512 thr (8 waves 2x4),
// BK=64, double-buffered LDS, reg-staged with f32->bf16 cvt.
// ---------------------------------------------------------------------------
__global__ __launch_bounds__(512, 1)
void xg_gemm(const float* __restrict__ x, const float* __restrict__ Wx,
             __hip_bfloat16* __restrict__ xg, int t0)
{
  __shared__ short8 As[2][1024];  // [buf][row*8 + swz(cg)], 128 rows x 8 granules
  __shared__ short8 Bs[2][1024];

  const int tid  = threadIdx.x;
  const int wave = tid >> 6;
  const int lane = tid & 63;

  // XCD-chunked swizzle (gridDim.x = W*64, always % 8 == 0)
  const int cpx = gridDim.x >> 3;
  const int nb  = (blockIdx.x & 7) * cpx + (blockIdx.x >> 3);
  const int nt  = nb & 31;   // 32 col tiles
  const int mt  = nb >> 5;

  const int trel  = mt >> 1;            // 128 rows span half a 256-batch block
  const int brow0 = (mt & 1) * 128;

  // staging: thread owns granules (r0,cg) and (r0+64,cg); granule = 16B = 8 bf16
  const int r0 = tid >> 3;   // 0..63
  const int cg = tid & 7;

  const float* asrc0 = x + ((size_t)(brow0 + r0) * T_STEPS + (t0 + trel)) * 1024 + cg * 8;
  const float* asrc1 = x + ((size_t)(brow0 + r0 + 64) * T_STEPS + (t0 + trel)) * 1024 + cg * 8;
  const float* bsrc0 = Wx + (size_t)(nt * 128 + r0) * 1024 + cg * 8;
  const float* bsrc1 = Wx + (size_t)(nt * 128 + r0 + 64) * 1024 + cg * 8;

  const int aslot0 = r0 * 8 + (cg ^ (r0 & 7));
  const int aslot1 = (r0 + 64) * 8 + (cg ^ (r0 & 7));   // (r0+64)&7 == r0&7

  f32x4 a0l, a0h, a1l, a1h, b0l, b0h, b1l, b1h;

#define XG_LOAD(KC)                                        \
  do {                                                     \
    a0l = *(const f32x4*)(asrc0 + (KC) * 64);              \
    a0h = *(const f32x4*)(asrc0 + (KC) * 64 + 4);          \
    a1l = *(const f32x4*)(asrc1 + (KC) * 64);              \
    a1h = *(const f32x4*)(asrc1 + (KC) * 64 + 4);          \
    b0l = *(const f32x4*)(bsrc0 + (KC) * 64);              \
    b0h = *(const f32x4*)(bsrc0 + (KC) * 64 + 4);          \
    b1l = *(const f32x4*)(bsrc1 + (KC) * 64);              \
    b1h = *(const f32x4*)(bsrc1 + (KC) * 64 + 4);          \
  } while (0)

#define XG_CVT1(lo, hi, dstarr, slot)                      \
  do {                                                     \
    short8 s_;                                             \
    _Pragma("unroll")                                      \
    for (int e = 0; e < 4; ++e) {                          \
      s_[e]     = f2bf((lo)[e]);                           \
      s_[e + 4] = f2bf((hi)[e]);                           \
    }                                                      \
    dstarr[slot] = s_;                                     \
  } while (0)

#define XG_WRITE(BUF)                                      \
  do {                                                     \
    XG_CVT1(a0l, a0h, As[BUF], aslot0);                    \
    XG_CVT1(a1l, a1h, As[BUF], aslot1);                    \
    XG_CVT1(b0l, b0h, Bs[BUF], aslot0);                    \
    XG_CVT1(b1l, b1h, Bs[BUF], aslot1);                    \
  } while (0)

  const int wr = wave >> 2;  // 0..1 : 64-row slab
  const int wc = wave & 3;   // 0..3 : 32-col slab

  f32x4 acc[4][2];
#pragma unroll
  for (int m = 0; m < 4; ++m)
#pragma unroll
    for (int n = 0; n < 2; ++n) acc[m][n] = (f32x4){0.f, 0.f, 0.f, 0.f};

  XG_LOAD(0);
  XG_WRITE(0);
  __syncthreads();

#pragma unroll 1
  for (int kc = 0; kc < 16; ++kc) {
    if (kc < 15) XG_LOAD(kc + 1);
    const int bs = kc & 1;
#pragma unroll
    for (int ks = 0; ks < 2; ++ks) {
      const int cgf = ks * 4 + (lane >> 4);
      short8 af[4], bfr[2];
#pragma unroll
      for (int m = 0; m < 4; ++m) {
        const int row = wr * 64 + m * 16 + (lane & 15);
        af[m] = As[bs][row * 8 + (cgf ^ (row & 7))];
      }
#pragma unroll
      for (int n = 0; n < 2; ++n) {
        const int row = wc * 32 + n * 16 + (lane & 15);
        bfr[n] = Bs[bs][row * 8 + (cgf ^ (row & 7))];
      }
#pragma unroll
      for (int m = 0; m < 4; ++m)
#pragma unroll
        for (int n = 0; n < 2; ++n)
          acc[m][n] = __builtin_amdgcn_mfma_f32_16x16x32_bf16(af[m], bfr[n], acc[m][n], 0, 0, 0);
    }
    if (kc < 15) XG_WRITE((kc + 1) & 1);
    __syncthreads();
  }

  const int dcol = lane & 15;
  const int dr0  = (lane >> 4) * 4;
#pragma unroll
  for (int m = 0; m < 4; ++m) {
#pragma unroll
    for (int n = 0; n < 2; ++n) {
      const int ocol = nt * 128 + wc * 32 + n * 16 + dcol;
#pragma unroll
      for (int rr = 0; rr < 4; ++rr) {
        const int orow = mt * 128 + wr * 64 + m * 16 + dr0 + rr;
        xg[(size_t)orow * GDIM + ocol] = __float2bfloat16(acc[m][n][rr]);
      }
    }
  }
#undef XG_LOAD
#undef XG_CVT1
#undef XG_WRITE
}

// ---------------------------------------------------------------------------
// LSTM step: gates = h_in @ Whb^T + xg_t + biasc; peephole cell; write h,c.
// Grid 256 x 512 thr. Tile 64(batch) x 64(16 cols x 4 gates). K=1024,
// 8 chunks of 128k, K split across wave halves (kh), double-buffered LDS,
// one barrier per chunk.
// ---------------------------------------------------------------------------
__global__ __launch_bounds__(512, 1)
void lstm_step(const __hip_bfloat16* __restrict__ xg_t,   // [256][4096]
               const __hip_bfloat16* __restrict__ Whb,    // [4096][1024]
               const float* __restrict__ biasc,
               const float* __restrict__ c2c,
               const __hip_bfloat16* __restrict__ h_in,
               __hip_bfloat16* __restrict__ h_out,
               float* __restrict__ c_st)
{
  __shared__ short8 As[2][1024];  // 64 rows x 16 granules (128 k)
  __shared__ short8 Bs[2][1024];

  const int tid  = threadIdx.x;
  const int wave = tid >> 6;
  const int lane = tid & 63;

  // XCD-aware: each XCD owns 8 ntiles -> its Wh slice (1 MB) stays L2-resident
  const int bid   = blockIdx.x;
  const int xcd   = bid & 7;
  const int idx   = bid >> 3;
  const int ntile = xcd * 8 + (idx & 7);   // 0..63
  const int mtile = idx >> 3;              // 0..3
  const int b0 = mtile * 64;
  const int j0 = ntile * 16;

  // staging: thread owns granules (r0,cg0) and (r0+32,cg0)
  const int r0  = tid >> 4;   // 0..31
  const int cg0 = tid & 15;

  const int aslot0 = r0 * 16 + (cg0 ^ (r0 & 7));
  const int aslot1 = (r0 + 32) * 16 + (cg0 ^ (r0 & 7));

  const int Brow0 = ((r0 >> 4)     ) * HDIM + j0 + (r0 & 15);  // gates 0,1
  const int Brow1 = ((r0 >> 4) + 2 ) * HDIM + j0 + (r0 & 15);  // gates 2,3
  const __hip_bfloat16* Wp0 = Whb + (size_t)Brow0 * HDIM + cg0 * 8;
  const __hip_bfloat16* Wp1 = Whb + (size_t)Brow1 * HDIM + cg0 * 8;
  const __hip_bfloat16* hp0 = h_in + (size_t)(b0 + r0) * HDIM + cg0 * 8;
  const __hip_bfloat16* hp1 = h_in + (size_t)(b0 + r0 + 32) * HDIM + cg0 * 8;

  short8 hv0, hv1, bv0, bv1;

#define LOADS(KC)                                                   \
  do {                                                              \
    bv0 = *(const short8*)(const void*)(Wp0 + (size_t)(KC) * 128);  \
    bv1 = *(const short8*)(const void*)(Wp1 + (size_t)(KC) * 128);  \
    hv0 = *(const short8*)(const void*)(hp0 + (size_t)(KC) * 128);  \
    hv1 = *(const short8*)(const void*)(hp1 + (size_t)(KC) * 128);  \
  } while (0)

#define WRITE_LDS(BUF)                                              \
  do {                                                              \
    As[BUF][aslot0] = hv0;                                          \
    As[BUF][aslot1] = hv1;                                          \
    Bs[BUF][aslot0] = bv0;                                          \
    Bs[BUF][aslot1] = bv1;                                          \
  } while (0)

  const int rf = wave & 3;   // row fragment (16 batch rows)
  const int kh = wave >> 2;  // k-half of each 128-k chunk
  const int arow = rf * 16 + (lane & 15);

  f32x4 acc[4];
#pragma unroll
  for (int f = 0; f < 4; ++f) acc[f] = (f32x4){0.f, 0.f, 0.f, 0.f};

  LOADS(0);
  WRITE_LDS(0);
  __syncthreads();

#pragma unroll 1
  for (int kc = 0; kc < 8; ++kc) {
    if (kc < 7) LOADS(kc + 1);
    const int bs = kc & 1;
#pragma unroll
    for (int ss = 0; ss < 2; ++ss) {
      const int colg = kh * 8 + ss * 4 + (lane >> 4);
      short8 af = As[bs][arow * 16 + (colg ^ (arow & 7))];
#pragma unroll
      for (int f = 0; f < 4; ++f) {
        const int br = f * 16 + (lane & 15);
        short8 bfq = Bs[bs][br * 16 + (colg ^ (br & 7))];
        acc[f] = __builtin_amdgcn_mfma_f32_16x16x32_bf16(af, bfq, acc[f], 0, 0, 0);
      }
    }
    if (kc < 7) WRITE_LDS((kc + 1) & 1);
    __syncthreads();
  }

  // ---- reduce k-halves via LDS, then fused cell ----
  float* red = (float*)&As[0][0];  // 64x64 f32 = 16 KB
  const int drow = (lane >> 4) * 4;
  const int dcol = lane & 15;
  if (kh == 1) {
#pragma unroll
    for (int f = 0; f < 4; ++f)
#pragma unroll
      for (int r = 0; r < 4; ++r)
        red[(rf * 16 + drow + r) * 64 + f * 16 + dcol] = acc[f][r];
  }
  __syncthreads();
  if (kh == 0) {
#pragma unroll
    for (int f = 0; f < 4; ++f)
#pragma unroll
      for (int r = 0; r < 4; ++r)
        acc[f][r] += red[(rf * 16 + drow + r) * 64 + f * 16 + dcol];

    const int j = j0 + dcol;
    const float bi = biasc[j];
    const float bf = biasc[HDIM + j];
    const float bg = biasc[2 * HDIM + j];
    const float bo = biasc[3 * HDIM + j];
    const float ci = c2c[j];
    const float cf = c2c[HDIM + j];
    const float co = c2c[2 * HDIM + j];
#pragma unroll
    for (int r = 0; r < 4; ++r) {
      const int b = b0 + rf * 16 + drow + r;
      const __hip_bfloat16* xr = xg_t + (size_t)b * GDIM + j;
      float x0 = __bfloat162float(xr[0]);
      float x1 = __bfloat162float(xr[HDIM]);
      float x2 = __bfloat162float(xr[2 * HDIM]);
      float x3 = __bfloat162float(xr[3 * HDIM]);
      float cp = c_st[(size_t)b * HDIM + j];
      float ig = sigmoidf_(acc[0][r] + x0 + bi + ci * cp);
      float fg = sigmoidf_(acc[1][r] + x1 + bf + cf * cp);
      float gg = tanh_(acc[2][r] + x2 + bg);
      float cn = fg * cp + ig * gg;
      float og = sigmoidf_(acc[3][r] + x3 + bo + co * cn);
      float hn = og * tanh_(cn);
      c_st[(size_t)b * HDIM + j] = cn;
      h_out[(size_t)b * HDIM + j] = __float2bfloat16(hn);
    }
  }
#undef LOADS
#undef WRITE_LDS
}

// ---------------------------------------------------------------------------
// Final FC: out[b][o] = h[b][:] . Wfc[o][:] + bfc[o]  (M=256,N=1024,K=1024)
// Wfc read f32, converted in staging.
// ---------------------------------------------------------------------------
__global__ __launch_bounds__(256, 1)
void fc_kernel(const __hip_bfloat16* __restrict__ h,
               const float* __restrict__ Wfc,
               const float* __restrict__ bfc,
               float* __restrict__ out)
{
  __shared__ short8 As8[512];  // 64 rows x 8 granules (64 k)
  __shared__ short8 Bs8[512];

  const int tid = threadIdx.x;
  const int wave = tid >> 6;
  const int lane = tid & 63;
  const int mtile = blockIdx.x >> 4;
  const int otile = blockIdx.x & 15;
  const int b0 = mtile * 64, o0 = otile * 64;

  const int r0 = tid >> 3;   // rows r0, r0+32
  const int cg0 = tid & 7;

  f32x4 acc[4];
#pragma unroll
  for (int f = 0; f < 4; ++f) acc[f] = (f32x4){0.f, 0.f, 0.f, 0.f};

#pragma unroll 1
  for (int kc = 0; kc < 16; ++kc) {
    __syncthreads();
    As8[r0 * 8 + (cg0 ^ (r0 & 7))] =
        *(const short8*)(const void*)(h + (size_t)(b0 + r0) * HDIM + kc * 64 + cg0 * 8);
    As8[(r0 + 32) * 8 + (cg0 ^ (r0 & 7))] =
        *(const short8*)(const void*)(h + (size_t)(b0 + r0 + 32) * HDIM + kc * 64 + cg0 * 8);
    {
      const float* p0 = Wfc + (size_t)(o0 + r0) * HDIM + kc * 64 + cg0 * 8;
      const float* p1 = Wfc + (size_t)(o0 + r0 + 32) * HDIM + kc * 64 + cg0 * 8;
      f32x4 l0 = *(const f32x4*)p0, h0 = *(const f32x4*)(p0 + 4);
      f32x4 l1 = *(const f32x4*)p1, h1 = *(const f32x4*)(p1 + 4);
      short8 s0, s1;
#pragma unroll
      for (int e = 0; e < 4; ++e) {
        s0[e] = f2bf(l0[e]); s0[e + 4] = f2bf(h0[e]);
        s1[e] = f2bf(l1[e]); s1[e + 4] = f2bf(h1[e]);
      }
      Bs8[r0 * 8 + (cg0 ^ (r0 & 7))] = s0;
      Bs8[(r0 + 32) * 8 + (cg0 ^ (r0 & 7))] = s1;
    }
    __syncthreads();
#pragma unroll
    for (int s = 0; s < 2; ++s) {
      const int colg = s * 4 + (lane >> 4);
      const int ar = wave * 16 + (lane & 15);
      short8 af = As8[ar * 8 + (colg ^ (ar & 7))];
#pragma unroll
      for (int f = 0; f < 4; ++f) {
        const int br = f * 16 + (lane & 15);
        short8 bfq = Bs8[br * 8 + (colg ^ (br & 7))];
        acc[f] = __builtin_amdgcn_mfma_f32_16x16x32_bf16(af, bfq, acc[f], 0, 0, 0);
      }
    }
  }

  const int dcol = lane & 15;
  const int drow = (lane >> 4) * 4;
#pragma unroll
  for (int f = 0; f < 4; ++f) {
    const int o = o0 + f * 16 + dcol;
    const float bias = bfc[o];
#pragma unroll
    for (int r = 0; r < 4; ++r) {
      const int b = b0 + wave * 16 + drow + r;
      out[(size_t)b * 1024 + o] = acc[f][r] + bias;
    }
  }
}

// ---------------------------------------------------------------------------
extern "C" void kernel_launch(void* const* d_in, const int* in_sizes, int n_in,
                              void* d_out, int out_size, void* d_ws, size_t ws_size,
                              hipStream_t stream)
{
  const float* x   = (const float*)d_in[0];
  const float* Wx  = (const float*)d_in[1];
  const float* bx  = (const float*)d_in[2];
  const float* Wh  = (const float*)d_in[3];
  const float* bh  = (const float*)d_in[4];
  const float* c2c = (const float*)d_in[5];
  const float* Wfc = (const float*)d_in[6];
  const float* bfc = (const float*)d_in[7];
  float* out = (float*)d_out;

  char* ws = (char*)d_ws;
  // layout:
  //   [0, 8M)            Whb bf16 [4096][1024]
  //   [8M, 8M+16K)       biasc f32 [4096]
  //   [8M+64K, +512K)    hb0
  //   [.. +512K)         hb1
  //   [8M+64K+1M, +1M)   c_st f32
  //   [11M, ...)         xg ring: W * 256 * 4096 bf16  (W*2MB)
  __hip_bfloat16* Whb   = (__hip_bfloat16*)(ws);
  float*          biasc = (float*)(ws + (8u << 20));
  __hip_bfloat16* hb0   = (__hip_bfloat16*)(ws + (8u << 20) + (1u << 16));
  __hip_bfloat16* hb1   = (__hip_bfloat16*)(ws + (8u << 20) + (1u << 16) + (1u << 19));
  float*          c_st  = (float*)(ws + (8u << 20) + (1u << 16) + (1u << 20));
  __hip_bfloat16* xgbuf = (__hip_bfloat16*)(ws + (11u << 20));

  // adaptive window: largest divisor of 512 whose ring fits in ws
  const size_t xg_off = (size_t)11 << 20;
  int W = 4;
  for (int cand = 512; cand >= 4; cand >>= 1) {
    size_t need = xg_off + (size_t)cand * BATCH * GDIM * sizeof(__hip_bfloat16);
    if (need <= ws_size) { W = cand; break; }
  }

  hipMemsetAsync(hb0, 0, (size_t)BATCH * HDIM * sizeof(__hip_bfloat16), stream);
  hipMemsetAsync(c_st, 0, (size_t)BATCH * HDIM * sizeof(float), stream);

  pack_kernel<<<1024, 256, 0, stream>>>(Wh, bx, bh, Whb, biasc);

  const int NW = T_STEPS / W;
  for (int w = 0; w < NW; ++w) {
    xg_gemm<<<W * 64, 512, 0, stream>>>(x, Wx, xgbuf, w * W);
    for (int tt = 0; tt < W; ++tt) {
      const int t = w * W + tt;
      const __hip_bfloat16* hin = (t & 1) ? hb1 : hb0;
      __hip_bfloat16* hout      = (t & 1) ? hb0 : hb1;
      lstm_step<<<256, 512, 0, stream>>>(xgbuf + (size_t)tt * BATCH * GDIM,
                                         Whb, biasc, c2c, hin, hout, c_st);
    }
  }

  fc_kernel<<<64, 256, 0, stream>>>(hb0, Wfc, bfc, out);
}